// Round 5
// baseline (179.224 us; speedup 1.0000x reference)
//
#include <hip/hip_runtime.h>
#include <math.h>

#define D_MODEL 300
#define LSEQ    512
#define NBATCH  300
#define SPLIT   16
#define LCH     (LSEQ / SPLIT)      // 32 l-values per diagA block
#define NG      4                   // parallel l-streams per diagA block
#define LPG     (LCH / NG)          // 8 l-values per stream
#define NR      75                  // float4 lanes per row (75*4 = 300)
#define TI      6                   // i-rows per termB block (300 = 50*6)
#define SPLITB  8                   // l-splits for termB
#define LCHB    (LSEQ / SPLITB)     // 64 l-values per termB block
#define SCALE   17.32050807568877f  // sqrt(300)

// pe[l, e]: e even -> sin(l * div[e/2]); e odd -> cos(l * div[e/2])
// Also zeros Dm (90000 floats < 153600 threads) so no separate memset dispatch.
__global__ void pe_kernel(float* __restrict__ pe, float* __restrict__ Dm) {
    int idx = blockIdx.x * blockDim.x + threadIdx.x;
    if (idx < D_MODEL * D_MODEL) Dm[idx] = 0.0f;
    if (idx >= LSEQ * D_MODEL) return;
    int l = idx / D_MODEL;
    int e = idx - l * D_MODEL;
    int k = e >> 1;
    float dv = expf((float)(2 * k) * (-9.210340371976184f / 300.0f));
    float arg = (float)l * dv;
    pe[idx] = (e & 1) ? cosf(arg) : sinf(arg);
}

// Term A: Dm[i][e] += SCALE * sum_{l in chunk} S[i][l] * emb1[x1[i,l]][e]
// S computed in-staging (each (i,l) is owned by exactly one block):
//   S[i][l] = emb2[x2[i,l]][i]*SCALE + pe[l][i]
__global__ void diagA_kernel(const int* __restrict__ x1, const int* __restrict__ x2,
                             const float* __restrict__ emb1, const float* __restrict__ emb2,
                             const float* __restrict__ pe, float* __restrict__ Dm) {
    __shared__ int    x1ch[LCH];
    __shared__ float  sch[LCH];
    __shared__ float4 part[NG][NR];
    const int i   = blockIdx.x;   // batch index (== diagonal index)
    const int sp  = blockIdx.y;   // l-chunk
    const int tid = threadIdx.x;
    const int l0  = sp * LCH;

    if (tid < LCH) {
        const int l = l0 + tid;
        x1ch[tid] = x1[i * LSEQ + l];
        const int v2 = x2[i * LSEQ + l];
        sch[tid] = (emb2[(size_t)v2 * D_MODEL + i] * SCALE + pe[l * D_MODEL + i]) * SCALE;
    }
    __syncthreads();

    const int g = tid / NR;       // l-stream
    const int r = tid - g * NR;   // float4 index within row

    if (tid < NG * NR) {
        const int lb = g * LPG;   // this stream owns l0+lb .. l0+lb+7
        const float4 v0 = ((const float4*)(emb1 + (size_t)x1ch[lb + 0] * D_MODEL))[r];
        const float4 v1 = ((const float4*)(emb1 + (size_t)x1ch[lb + 1] * D_MODEL))[r];
        const float4 v2 = ((const float4*)(emb1 + (size_t)x1ch[lb + 2] * D_MODEL))[r];
        const float4 v3 = ((const float4*)(emb1 + (size_t)x1ch[lb + 3] * D_MODEL))[r];
        const float4 v4 = ((const float4*)(emb1 + (size_t)x1ch[lb + 4] * D_MODEL))[r];
        const float4 v5 = ((const float4*)(emb1 + (size_t)x1ch[lb + 5] * D_MODEL))[r];
        const float4 v6 = ((const float4*)(emb1 + (size_t)x1ch[lb + 6] * D_MODEL))[r];
        const float4 v7 = ((const float4*)(emb1 + (size_t)x1ch[lb + 7] * D_MODEL))[r];
        const float s0 = sch[lb + 0], s1 = sch[lb + 1], s2 = sch[lb + 2], s3 = sch[lb + 3];
        const float s4 = sch[lb + 4], s5 = sch[lb + 5], s6 = sch[lb + 6], s7 = sch[lb + 7];
        float ax, ay, az, aw;
        ax = s0 * v0.x;            ay = s0 * v0.y;            az = s0 * v0.z;            aw = s0 * v0.w;
        ax = fmaf(s1, v1.x, ax);   ay = fmaf(s1, v1.y, ay);   az = fmaf(s1, v1.z, az);   aw = fmaf(s1, v1.w, aw);
        ax = fmaf(s2, v2.x, ax);   ay = fmaf(s2, v2.y, ay);   az = fmaf(s2, v2.z, az);   aw = fmaf(s2, v2.w, aw);
        ax = fmaf(s3, v3.x, ax);   ay = fmaf(s3, v3.y, ay);   az = fmaf(s3, v3.z, az);   aw = fmaf(s3, v3.w, aw);
        ax = fmaf(s4, v4.x, ax);   ay = fmaf(s4, v4.y, ay);   az = fmaf(s4, v4.z, az);   aw = fmaf(s4, v4.w, aw);
        ax = fmaf(s5, v5.x, ax);   ay = fmaf(s5, v5.y, ay);   az = fmaf(s5, v5.z, az);   aw = fmaf(s5, v5.w, aw);
        ax = fmaf(s6, v6.x, ax);   ay = fmaf(s6, v6.y, ay);   az = fmaf(s6, v6.z, az);   aw = fmaf(s6, v6.w, aw);
        ax = fmaf(s7, v7.x, ax);   ay = fmaf(s7, v7.y, ay);   az = fmaf(s7, v7.z, az);   aw = fmaf(s7, v7.w, aw);
        part[g][r] = make_float4(ax, ay, az, aw);
    }
    __syncthreads();

    if (g == 0 && tid < NR) {
        float4 p0 = part[0][r], p1 = part[1][r], p2 = part[2][r], p3 = part[3][r];
        float* dst = Dm + i * D_MODEL + 4 * r;
        atomicAdd(dst + 0, p0.x + p1.x + p2.x + p3.x);
        atomicAdd(dst + 1, p0.y + p1.y + p2.y + p3.y);
        atomicAdd(dst + 2, p0.z + p1.z + p2.z + p3.z);
        atomicAdd(dst + 3, p0.w + p1.w + p2.w + p3.w);
    }
}

// Term B: Dm[i][e] += sum_l S[i][l] * pe[l][e]
// S computed in-staging (each (i,l) owned by exactly one termB block).
// 400 blocks, 64 l's per block.
__global__ void termB_kernel(const int* __restrict__ x2, const float* __restrict__ emb2,
                             const float* __restrict__ pe, float* __restrict__ Dm) {
    __shared__ float sS[TI][LCHB];   // 6*64*4 = 1536 B
    const int i0  = blockIdx.x * TI;
    const int l0  = blockIdx.y * LCHB;
    const int tid = threadIdx.x;

    for (int t = tid; t < TI * LCHB; t += 320) {
        const int ti = t >> 6;           // / LCHB
        const int l  = t & (LCHB - 1);
        const int gi = i0 + ti;
        const int gl = l0 + l;
        const int v2 = x2[gi * LSEQ + gl];
        sS[ti][l] = emb2[(size_t)v2 * D_MODEL + gi] * SCALE + pe[gl * D_MODEL + gi];
    }
    __syncthreads();

    if (tid < D_MODEL) {
        float acc0 = 0.f, acc1 = 0.f, acc2 = 0.f, acc3 = 0.f, acc4 = 0.f, acc5 = 0.f;
        #pragma unroll 8
        for (int l = 0; l < LCHB; l += 4) {
            float p0 = pe[(l0 + l + 0) * D_MODEL + tid];
            float p1 = pe[(l0 + l + 1) * D_MODEL + tid];
            float p2 = pe[(l0 + l + 2) * D_MODEL + tid];
            float p3 = pe[(l0 + l + 3) * D_MODEL + tid];
            acc0 = fmaf(sS[0][l + 0], p0, acc0); acc0 = fmaf(sS[0][l + 1], p1, acc0);
            acc0 = fmaf(sS[0][l + 2], p2, acc0); acc0 = fmaf(sS[0][l + 3], p3, acc0);
            acc1 = fmaf(sS[1][l + 0], p0, acc1); acc1 = fmaf(sS[1][l + 1], p1, acc1);
            acc1 = fmaf(sS[1][l + 2], p2, acc1); acc1 = fmaf(sS[1][l + 3], p3, acc1);
            acc2 = fmaf(sS[2][l + 0], p0, acc2); acc2 = fmaf(sS[2][l + 1], p1, acc2);
            acc2 = fmaf(sS[2][l + 2], p2, acc2); acc2 = fmaf(sS[2][l + 3], p3, acc2);
            acc3 = fmaf(sS[3][l + 0], p0, acc3); acc3 = fmaf(sS[3][l + 1], p1, acc3);
            acc3 = fmaf(sS[3][l + 2], p2, acc3); acc3 = fmaf(sS[3][l + 3], p3, acc3);
            acc4 = fmaf(sS[4][l + 0], p0, acc4); acc4 = fmaf(sS[4][l + 1], p1, acc4);
            acc4 = fmaf(sS[4][l + 2], p2, acc4); acc4 = fmaf(sS[4][l + 3], p3, acc4);
            acc5 = fmaf(sS[5][l + 0], p0, acc5); acc5 = fmaf(sS[5][l + 1], p1, acc5);
            acc5 = fmaf(sS[5][l + 2], p2, acc5); acc5 = fmaf(sS[5][l + 3], p3, acc5);
        }
        atomicAdd(&Dm[(i0 + 0) * D_MODEL + tid], acc0);
        atomicAdd(&Dm[(i0 + 1) * D_MODEL + tid], acc1);
        atomicAdd(&Dm[(i0 + 2) * D_MODEL + tid], acc2);
        atomicAdd(&Dm[(i0 + 3) * D_MODEL + tid], acc3);
        atomicAdd(&Dm[(i0 + 4) * D_MODEL + tid], acc4);
        atomicAdd(&Dm[(i0 + 5) * D_MODEL + tid], acc5);
    }
}

// fc1, full-K per j-row: Hpre[j][e] = relu(b1[j] + sum_k w1[j,k] * Dm[k][e])
// No atomics, no Hpre memset; bias+relu folded into the store.
__global__ void fc1_kernel(const float* __restrict__ w1, const float* __restrict__ Dm,
                           const float* __restrict__ b1, float* __restrict__ Hpre) {
    const int j   = blockIdx.x;
    const int tid = threadIdx.x;
    if (tid >= D_MODEL) return;
    const float* w1r = w1 + j * D_MODEL;
    float acc = 0.0f;
    #pragma unroll 4
    for (int k = 0; k < D_MODEL; ++k) {
        acc = fmaf(w1r[k], Dm[k * D_MODEL + tid], acc);
    }
    Hpre[j * D_MODEL + tid] = fmaxf(acc + b1[j], 0.0f);
}

// Fused fc2 + softmax (Hpre is already relu'd). Block = 256 = 64 e-lanes x 4 j-chunks.
__global__ void fc2_softmax_kernel(const float* __restrict__ Hpre, const float* __restrict__ w2,
                                   const float* __restrict__ b2, float* __restrict__ out) {
    __shared__ float sm[4][4][64];   // [jc][o][e_loc]
    const int tid   = threadIdx.x;
    const int e_loc = tid & 63;
    const int jc    = tid >> 6;
    const int e     = blockIdx.x * 64 + e_loc;

    float a0 = 0.f, a1 = 0.f, a2 = 0.f, a3 = 0.f;
    if (e < D_MODEL) {
        const int j0 = jc * 75;
        #pragma unroll 5
        for (int j = j0; j < j0 + 75; ++j) {
            float h = Hpre[j * D_MODEL + e];
            a0 = fmaf(h, w2[0 * D_MODEL + j], a0);
            a1 = fmaf(h, w2[1 * D_MODEL + j], a1);
            a2 = fmaf(h, w2[2 * D_MODEL + j], a2);
            a3 = fmaf(h, w2[3 * D_MODEL + j], a3);
        }
    }
    sm[jc][0][e_loc] = a0; sm[jc][1][e_loc] = a1;
    sm[jc][2][e_loc] = a2; sm[jc][3][e_loc] = a3;
    __syncthreads();

    if (jc == 0 && e < D_MODEL) {
        float l0 = b2[0] + sm[0][0][e_loc] + sm[1][0][e_loc] + sm[2][0][e_loc] + sm[3][0][e_loc];
        float l1 = b2[1] + sm[0][1][e_loc] + sm[1][1][e_loc] + sm[2][1][e_loc] + sm[3][1][e_loc];
        float l2 = b2[2] + sm[0][2][e_loc] + sm[1][2][e_loc] + sm[2][2][e_loc] + sm[3][2][e_loc];
        float l3 = b2[3] + sm[0][3][e_loc] + sm[1][3][e_loc] + sm[2][3][e_loc] + sm[3][3][e_loc];
        float m  = fmaxf(fmaxf(l0, l1), fmaxf(l2, l3));
        float x0 = expf(l0 - m), x1 = expf(l1 - m), x2 = expf(l2 - m), x3 = expf(l3 - m);
        float inv = 1.0f / (x0 + x1 + x2 + x3);
        out[e * 4 + 0] = x0 * inv;
        out[e * 4 + 1] = x1 * inv;
        out[e * 4 + 2] = x2 * inv;
        out[e * 4 + 3] = x3 * inv;
    }
}

extern "C" void kernel_launch(void* const* d_in, const int* in_sizes, int n_in,
                              void* d_out, int out_size, void* d_ws, size_t ws_size,
                              hipStream_t stream) {
    const int*   x1   = (const int*)d_in[0];
    const int*   x2   = (const int*)d_in[1];
    const float* emb1 = (const float*)d_in[2];
    const float* emb2 = (const float*)d_in[3];
    const float* w1   = (const float*)d_in[4];
    const float* b1   = (const float*)d_in[5];
    const float* w2   = (const float*)d_in[6];
    const float* b2   = (const float*)d_in[7];
    float* out = (float*)d_out;

    char* ws = (char*)d_ws;
    float* pe   = (float*)ws;                  // 512*300*4 = 614400 B
    float* Dm   = (float*)(ws + 614400);       // 300*300*4 = 360000 B
    float* Hpre = (float*)(ws + 974400);       // 300*300*4 = 360000 B

    pe_kernel<<<(LSEQ * D_MODEL + 255) / 256, 256, 0, stream>>>(pe, Dm);
    diagA_kernel<<<dim3(NBATCH, SPLIT), 320, 0, stream>>>(x1, x2, emb1, emb2, pe, Dm);
    termB_kernel<<<dim3(NBATCH / TI, SPLITB), 320, 0, stream>>>(x2, emb2, pe, Dm);
    fc1_kernel<<<NBATCH, 320, 0, stream>>>(w1, Dm, b1, Hpre);
    fc2_softmax_kernel<<<(D_MODEL + 63) / 64, 256, 0, stream>>>(Hpre, w2, b2, out);
}

// Round 6
// 154.839 us; speedup vs baseline: 1.1575x; 1.1575x over previous
//
#include <hip/hip_runtime.h>
#include <math.h>

#define D_MODEL 300
#define LSEQ    512
#define NBATCH  300
#define SPLIT   16
#define LCH     (LSEQ / SPLIT)      // 32 l-values per diagAB block
#define NG      4                   // parallel l-streams per block
#define LPG     (LCH / NG)          // 8 l-values per stream
#define NR      75                  // float4 lanes per row (75*4 = 300)
#define KCH     (D_MODEL / 4)       // 75, fc1 k-chunk
#define JPB     2                   // j-rows per fc1 block
#define SCALE   17.32050807568877f  // sqrt(300)
#define C2      0.030701134573253947f  // ln(10000)/300
#define PIH     1.5707963267948966f    // pi/2 (cos x = sin(x+pi/2))

// Fused diag kernel: Dm[i][e] += sum_{l in chunk} S[l] * (SCALE*emb1[x1[i,l]][e] + pe[l][e])
//  - S[l] = emb2[x2[i,l]][i]*SCALE + pe[l][i], computed in staging (pe inline)
//  - term A: 8 unrolled float4 gathers of emb1 rows
//  - term B: pe computed in-register (2 expf + sin/cos per l) -> no pe table at all.
__global__ void diagAB_kernel(const int* __restrict__ x1, const int* __restrict__ x2,
                              const float* __restrict__ emb1, const float* __restrict__ emb2,
                              float* __restrict__ Dm) {
    __shared__ int    x1ch[LCH];
    __shared__ float  sch[LCH];   // raw S values
    __shared__ float4 part[NG][NR];
    const int i   = blockIdx.x;   // batch index (== diagonal index)
    const int sp  = blockIdx.y;   // l-chunk
    const int tid = threadIdx.x;
    const int l0  = sp * LCH;

    if (tid < LCH) {
        const int l = l0 + tid;
        x1ch[tid] = x1[i * LSEQ + l];
        const int v2 = x2[i * LSEQ + l];
        const float dvi = __expf(-C2 * (float)(i & ~1));
        const float arg = (float)l * dvi + ((i & 1) ? PIH : 0.0f);
        sch[tid] = fmaf(emb2[(size_t)v2 * D_MODEL + i], SCALE, __sinf(arg));
    }
    __syncthreads();

    const int g = tid / NR;       // l-stream
    const int r = tid - g * NR;   // float4 index within row (e = 4r..4r+3)

    if (tid < NG * NR) {
        const int lb = g * LPG;   // this stream owns l0+lb .. l0+lb+7
        // ---- term A: 8 independent row gathers ----
        const float4 v0 = ((const float4*)(emb1 + (size_t)x1ch[lb + 0] * D_MODEL))[r];
        const float4 v1 = ((const float4*)(emb1 + (size_t)x1ch[lb + 1] * D_MODEL))[r];
        const float4 v2 = ((const float4*)(emb1 + (size_t)x1ch[lb + 2] * D_MODEL))[r];
        const float4 v3 = ((const float4*)(emb1 + (size_t)x1ch[lb + 3] * D_MODEL))[r];
        const float4 v4 = ((const float4*)(emb1 + (size_t)x1ch[lb + 4] * D_MODEL))[r];
        const float4 v5 = ((const float4*)(emb1 + (size_t)x1ch[lb + 5] * D_MODEL))[r];
        const float4 v6 = ((const float4*)(emb1 + (size_t)x1ch[lb + 6] * D_MODEL))[r];
        const float4 v7 = ((const float4*)(emb1 + (size_t)x1ch[lb + 7] * D_MODEL))[r];
        const float s0 = sch[lb + 0], s1 = sch[lb + 1], s2 = sch[lb + 2], s3 = sch[lb + 3];
        const float s4 = sch[lb + 4], s5 = sch[lb + 5], s6 = sch[lb + 6], s7 = sch[lb + 7];
        const float t0 = s0 * SCALE, t1 = s1 * SCALE, t2 = s2 * SCALE, t3 = s3 * SCALE;
        const float t4 = s4 * SCALE, t5 = s5 * SCALE, t6 = s6 * SCALE, t7 = s7 * SCALE;
        float ax, ay, az, aw;
        ax = t0 * v0.x;            ay = t0 * v0.y;            az = t0 * v0.z;            aw = t0 * v0.w;
        ax = fmaf(t1, v1.x, ax);   ay = fmaf(t1, v1.y, ay);   az = fmaf(t1, v1.z, az);   aw = fmaf(t1, v1.w, aw);
        ax = fmaf(t2, v2.x, ax);   ay = fmaf(t2, v2.y, ay);   az = fmaf(t2, v2.z, az);   aw = fmaf(t2, v2.w, aw);
        ax = fmaf(t3, v3.x, ax);   ay = fmaf(t3, v3.y, ay);   az = fmaf(t3, v3.z, az);   aw = fmaf(t3, v3.w, aw);
        ax = fmaf(t4, v4.x, ax);   ay = fmaf(t4, v4.y, ay);   az = fmaf(t4, v4.z, az);   aw = fmaf(t4, v4.w, aw);
        ax = fmaf(t5, v5.x, ax);   ay = fmaf(t5, v5.y, ay);   az = fmaf(t5, v5.z, az);   aw = fmaf(t5, v5.w, aw);
        ax = fmaf(t6, v6.x, ax);   ay = fmaf(t6, v6.y, ay);   az = fmaf(t6, v6.z, az);   aw = fmaf(t6, v6.w, aw);
        ax = fmaf(t7, v7.x, ax);   ay = fmaf(t7, v7.y, ay);   az = fmaf(t7, v7.z, az);   aw = fmaf(t7, v7.w, aw);

        // ---- term B: pe in-register. e = 4r+{0,1,2,3}; (e&~1) = {4r,4r,4r+2,4r+2} ----
        const float dvA = __expf(-C2 * (float)(4 * r));
        const float dvB = __expf(-C2 * (float)(4 * r + 2));
        const float s8[LPG] = {s0, s1, s2, s3, s4, s5, s6, s7};
        #pragma unroll
        for (int q = 0; q < LPG; ++q) {
            const float fl = (float)(l0 + lb + q);
            const float aA = fl * dvA;
            const float aB = fl * dvB;
            ax = fmaf(s8[q], __sinf(aA), ax);
            ay = fmaf(s8[q], __cosf(aA), ay);
            az = fmaf(s8[q], __sinf(aB), az);
            aw = fmaf(s8[q], __cosf(aB), aw);
        }
        part[g][r] = make_float4(ax, ay, az, aw);
    }
    __syncthreads();

    if (g == 0 && tid < NR) {
        float4 p0 = part[0][r], p1 = part[1][r], p2 = part[2][r], p3 = part[3][r];
        float* dst = Dm + i * D_MODEL + 4 * r;
        atomicAdd(dst + 0, p0.x + p1.x + p2.x + p3.x);
        atomicAdd(dst + 1, p0.y + p1.y + p2.y + p3.y);
        atomicAdd(dst + 2, p0.z + p1.z + p2.z + p3.z);
        atomicAdd(dst + 3, p0.w + p1.w + p2.w + p3.w);
    }
}

// fc1 k-split partial (proven ~6 us form): Hpre[j][e] += sum_{k in chunk} w1[j,k]*Dm[k][e]
__global__ void fc1_kernel(const float* __restrict__ w1, const float* __restrict__ Dm,
                           float* __restrict__ Hpre) {
    const int j0  = blockIdx.x * JPB;
    const int sp  = blockIdx.y;
    const int tid = threadIdx.x;
    const int k0  = sp * KCH;
    if (tid >= D_MODEL) return;
    const float* w1r0 = w1 + (j0 + 0) * D_MODEL + k0;
    const float* w1r1 = w1 + (j0 + 1) * D_MODEL + k0;
    float acc0 = 0.0f, acc1 = 0.0f;
    #pragma unroll 5
    for (int k = 0; k < KCH; ++k) {
        float d = Dm[(k0 + k) * D_MODEL + tid];
        acc0 = fmaf(w1r0[k], d, acc0);
        acc1 = fmaf(w1r1[k], d, acc1);
    }
    atomicAdd(&Hpre[(j0 + 0) * D_MODEL + tid], acc0);
    atomicAdd(&Hpre[(j0 + 1) * D_MODEL + tid], acc1);
}

// Fused bias + relu + fc2 + softmax. Block = 256 thr = 64 e-lanes x 4 j-chunks.
__global__ void fc2_softmax_kernel(const float* __restrict__ Hpre, const float* __restrict__ b1,
                                   const float* __restrict__ w2, const float* __restrict__ b2,
                                   float* __restrict__ out) {
    __shared__ float sm[4][4][64];   // [jc][o][e_loc]
    const int tid   = threadIdx.x;
    const int e_loc = tid & 63;
    const int jc    = tid >> 6;
    const int e     = blockIdx.x * 64 + e_loc;

    float a0 = 0.f, a1 = 0.f, a2 = 0.f, a3 = 0.f;
    if (e < D_MODEL) {
        const int j0 = jc * 75;
        #pragma unroll 5
        for (int j = j0; j < j0 + 75; ++j) {
            float h = fmaxf(Hpre[j * D_MODEL + e] + b1[j], 0.0f);
            a0 = fmaf(h, w2[0 * D_MODEL + j], a0);
            a1 = fmaf(h, w2[1 * D_MODEL + j], a1);
            a2 = fmaf(h, w2[2 * D_MODEL + j], a2);
            a3 = fmaf(h, w2[3 * D_MODEL + j], a3);
        }
    }
    sm[jc][0][e_loc] = a0; sm[jc][1][e_loc] = a1;
    sm[jc][2][e_loc] = a2; sm[jc][3][e_loc] = a3;
    __syncthreads();

    if (jc == 0 && e < D_MODEL) {
        float l0 = b2[0] + sm[0][0][e_loc] + sm[1][0][e_loc] + sm[2][0][e_loc] + sm[3][0][e_loc];
        float l1 = b2[1] + sm[0][1][e_loc] + sm[1][1][e_loc] + sm[2][1][e_loc] + sm[3][1][e_loc];
        float l2 = b2[2] + sm[0][2][e_loc] + sm[1][2][e_loc] + sm[2][2][e_loc] + sm[3][2][e_loc];
        float l3 = b2[3] + sm[0][3][e_loc] + sm[1][3][e_loc] + sm[2][3][e_loc] + sm[3][3][e_loc];
        float m  = fmaxf(fmaxf(l0, l1), fmaxf(l2, l3));
        float x0 = expf(l0 - m), x1 = expf(l1 - m), x2 = expf(l2 - m), x3 = expf(l3 - m);
        float inv = 1.0f / (x0 + x1 + x2 + x3);
        out[e * 4 + 0] = x0 * inv;
        out[e * 4 + 1] = x1 * inv;
        out[e * 4 + 2] = x2 * inv;
        out[e * 4 + 3] = x3 * inv;
    }
}

extern "C" void kernel_launch(void* const* d_in, const int* in_sizes, int n_in,
                              void* d_out, int out_size, void* d_ws, size_t ws_size,
                              hipStream_t stream) {
    const int*   x1   = (const int*)d_in[0];
    const int*   x2   = (const int*)d_in[1];
    const float* emb1 = (const float*)d_in[2];
    const float* emb2 = (const float*)d_in[3];
    const float* w1   = (const float*)d_in[4];
    const float* b1   = (const float*)d_in[5];
    const float* w2   = (const float*)d_in[6];
    const float* b2   = (const float*)d_in[7];
    float* out = (float*)d_out;

    char* ws = (char*)d_ws;
    float* Dm   = (float*)ws;                  // 300*300*4 = 360000 B
    float* Hpre = (float*)(ws + 360000);       // 300*300*4 = 360000 B

    // zero both atomic-accumulated buffers (contiguous, 720 KB ~ 0.1 us)
    (void)hipMemsetAsync(Dm, 0, 2 * 360000, stream);

    diagAB_kernel<<<dim3(NBATCH, SPLIT), 320, 0, stream>>>(x1, x2, emb1, emb2, Dm);
    fc1_kernel<<<dim3(D_MODEL / JPB, 4), 320, 0, stream>>>(w1, Dm, Hpre);
    fc2_softmax_kernel<<<(D_MODEL + 63) / 64, 256, 0, stream>>>(Hpre, b1, w2, b2, out);
}